// Round 1
// baseline (1069.679 us; speedup 1.0000x reference)
//
#include <hip/hip_runtime.h>

namespace {
constexpr int Sdim = 2048;
constexpr int Ddim = 64;
constexpr int BQ = 64;
constexpr int BK = 64;
constexpr int SP = 68;          // padded stride for P^T (16B-aligned rows, 8-way worst case on writes)
constexpr int NT = 256;

__global__ __launch_bounds__(NT, 2)
void attn_fwd(const float* __restrict__ Qg, const float* __restrict__ Kg,
              const float* __restrict__ Vg, const float* __restrict__ Mg,
              float* __restrict__ Og) {
  __shared__ __align__(16) float sQT[Ddim * BQ];   // [d][r], Q^T, pre-scaled by 0.125
  __shared__ __align__(16) float sU[BK * SP];      // union: K^T [d][c] (stride BK) then P^T [k][r] (stride SP)
  __shared__ __align__(16) float sVt[BK * Ddim];   // [k][d]

  const int t  = threadIdx.x;
  const int tx = t & 15;
  const int ty = t >> 4;
  const int r  = ty * 4;        // 4 query rows owned by this thread
  const int c  = tx * 4;        // 4 key cols (score stage) / 4 d cols (PV stage)

  const int bh = blockIdx.y;    // b*16 + h
  const int b  = bh >> 4;
  const int q0 = blockIdx.x * BQ;

  const float* Qb = Qg + ((size_t)bh * Sdim + q0) * Ddim;
  const float* Kb = Kg + (size_t)bh * Sdim * Ddim;
  const float* Vb = Vg + (size_t)bh * Sdim * Ddim;
  const float* Mb = Mg + ((size_t)b * Sdim + q0) * Sdim;

  // ---- stage Q^T once, scaled by 1/sqrt(64) = 0.125 ----
#pragma unroll
  for (int rep = 0; rep < 4; ++rep) {
    int idx = t + rep * NT;          // 0..1023 float4s
    int row = idx & 63;              // lane-consecutive rows -> conflict-free LDS writes
    int d4  = idx >> 6;              // wave-uniform d-group
    float4 v = *(const float4*)(Qb + row * Ddim + d4 * 4);
    sQT[(d4 * 4 + 0) * BQ + row] = v.x * 0.125f;
    sQT[(d4 * 4 + 1) * BQ + row] = v.y * 0.125f;
    sQT[(d4 * 4 + 2) * BQ + row] = v.z * 0.125f;
    sQT[(d4 * 4 + 3) * BQ + row] = v.w * 0.125f;
  }

  float accO[4][4] = {{0.f, 0.f, 0.f, 0.f}};
  float rs[4] = {0.f, 0.f, 0.f, 0.f};

  for (int kt = 0; kt < Sdim / BK; ++kt) {
    const int k0 = kt * BK;
    __syncthreads();                  // previous tile's PV reads done before overwrite
    // ---- stage K^T into sU (stride BK) ----
#pragma unroll
    for (int rep = 0; rep < 4; ++rep) {
      int idx = t + rep * NT;
      int row = idx & 63;
      int d4  = idx >> 6;
      float4 v = *(const float4*)(Kb + (size_t)(k0 + row) * Ddim + d4 * 4);
      sU[(d4 * 4 + 0) * BK + row] = v.x;
      sU[(d4 * 4 + 1) * BK + row] = v.y;
      sU[(d4 * 4 + 2) * BK + row] = v.z;
      sU[(d4 * 4 + 3) * BK + row] = v.w;
    }
    // ---- stage V natural [k][d] ----
#pragma unroll
    for (int rep = 0; rep < 4; ++rep) {
      int idx = t + rep * NT;
      int row = idx >> 4;
      int d4  = idx & 15;
      *(float4*)(sVt + row * Ddim + d4 * 4) =
          *(const float4*)(Vb + (size_t)(k0 + row) * Ddim + d4 * 4);
    }
    __syncthreads();

    // ---- scores: acc[i][j] = (Q*0.125) . K  for rows r+i, cols c+j ----
    float acc[4][4] = {{0.f, 0.f, 0.f, 0.f}};
#pragma unroll 8
    for (int d = 0; d < Ddim; ++d) {
      float4 qv = *(const float4*)(sQT + d * BQ + r);   // 4 rows at dim d
      float4 kv = *(const float4*)(sU  + d * BK + c);   // 4 cols at dim d
      float qr[4] = {qv.x, qv.y, qv.z, qv.w};
      float kc[4] = {kv.x, kv.y, kv.z, kv.w};
#pragma unroll
      for (int i = 0; i < 4; ++i)
#pragma unroll
        for (int j = 0; j < 4; ++j)
          acc[i][j] = fmaf(qr[i], kc[j], acc[i][j]);
    }

    // ---- p = exp(s) * mask; accumulate row sums ----
#pragma unroll
    for (int i = 0; i < 4; ++i) {
      float4 m = *(const float4*)(Mb + (size_t)(r + i) * Sdim + k0 + c);
      float p0 = __expf(acc[i][0]) * m.x;
      float p1 = __expf(acc[i][1]) * m.y;
      float p2 = __expf(acc[i][2]) * m.z;
      float p3 = __expf(acc[i][3]) * m.w;
      rs[i] += (p0 + p1) + (p2 + p3);
      acc[i][0] = p0; acc[i][1] = p1; acc[i][2] = p2; acc[i][3] = p3;
    }

    __syncthreads();                  // all K^T reads done before P^T overwrites sU
#pragma unroll
    for (int j = 0; j < 4; ++j) {
      float4 w = make_float4(acc[0][j], acc[1][j], acc[2][j], acc[3][j]);
      *(float4*)(sU + (c + j) * SP + r) = w;   // P^T[k=c+j][rows r..r+3]
    }
    __syncthreads();                  // P^T visible

    // ---- O += P @ V ----
#pragma unroll 8
    for (int k = 0; k < BK; ++k) {
      float4 pv = *(const float4*)(sU  + k * SP + r);    // P rows r..r+3 at key k
      float4 vv = *(const float4*)(sVt + k * Ddim + c);  // V dims c..c+3 at key k
      float pr[4] = {pv.x, pv.y, pv.z, pv.w};
      float vc[4] = {vv.x, vv.y, vv.z, vv.w};
#pragma unroll
      for (int i = 0; i < 4; ++i)
#pragma unroll
        for (int j = 0; j < 4; ++j)
          accO[i][j] = fmaf(pr[i], vc[j], accO[i][j]);
    }
  }

  // ---- reduce row sums across the 16 tx lanes (same rows) ----
#pragma unroll
  for (int i = 0; i < 4; ++i) {
    float v = rs[i];
    v += __shfl_xor(v, 1);
    v += __shfl_xor(v, 2);
    v += __shfl_xor(v, 4);
    v += __shfl_xor(v, 8);
    rs[i] = v + 1e-8f;
  }

  float* Ob = Og + ((size_t)bh * Sdim + q0) * Ddim;
#pragma unroll
  for (int i = 0; i < 4; ++i) {
    float inv = 1.0f / rs[i];
    float4 w = make_float4(accO[i][0] * inv, accO[i][1] * inv,
                           accO[i][2] * inv, accO[i][3] * inv);
    *(float4*)(Ob + (size_t)(r + i) * Ddim + c) = w;
  }
}
} // namespace

extern "C" void kernel_launch(void* const* d_in, const int* in_sizes, int n_in,
                              void* d_out, int out_size, void* d_ws, size_t ws_size,
                              hipStream_t stream) {
  const float* Q = (const float*)d_in[0];
  const float* K = (const float*)d_in[1];
  const float* V = (const float*)d_in[2];
  const float* M = (const float*)d_in[3];
  float* O = (float*)d_out;
  dim3 grid(Sdim / BQ, 4 * 16);
  attn_fwd<<<grid, NT, 0, stream>>>(Q, K, V, M, O);
}

// Round 2
// 410.927 us; speedup vs baseline: 2.6031x; 2.6031x over previous
//
#include <hip/hip_runtime.h>

namespace {
constexpr int S  = 2048;
constexpr int D  = 64;
constexpr int BQ = 64;   // q-rows per block (16 per wave)
constexpr int BK = 64;   // keys per tile
constexpr int NT = 256;
constexpr int STR = 72;  // LDS row stride in bf16 elems (144 B: 16B-aligned, bank-spread)

typedef short bf16x8 __attribute__((ext_vector_type(8)));
typedef float f32x4  __attribute__((ext_vector_type(4)));

__device__ inline unsigned short bf16c(float x) {
  __bf16 h = (__bf16)x;
  return __builtin_bit_cast(unsigned short, h);
}
__device__ inline unsigned pk2(float a, float b) {
  return (unsigned)bf16c(a) | ((unsigned)bf16c(b) << 16);
}

__global__ __launch_bounds__(NT, 2)
void attn_mfma(const float* __restrict__ Qg, const float* __restrict__ Kg,
               const float* __restrict__ Vg, const float* __restrict__ Mg,
               float* __restrict__ Og) {
  __shared__ __align__(16) unsigned short sK[BK * STR];     // [key][d]   bf16
  __shared__ __align__(16) unsigned short sVt[D * STR];     // [d][key]   bf16 (transposed)
  __shared__ __align__(16) unsigned short sP[4 * 16 * STR]; // per-wave [m][k] bf16

  const int t    = threadIdx.x;
  const int wave = t >> 6;
  const int lane = t & 63;
  const int quad = lane >> 4;
  const int n16  = lane & 15;
  const int odd  = lane & 1;

  const int bh = blockIdx.y;
  const int b  = bh >> 4;
  const int q0 = blockIdx.x * BQ;

  const float* Qb = Qg + ((size_t)bh * S + q0 + wave * 16) * D;
  const float* Kb = Kg + (size_t)bh * S * D;
  const float* Vb = Vg + (size_t)bh * S * D;
  const float* Mb = Mg + (size_t)b * S * S + (size_t)(q0 + wave * 16) * S;

  // ---- Q A-frags (A[m=lane&15][k=quad*8+j]), pre-scaled by 1/sqrt(64) ----
  bf16x8 aq[2];
#pragma unroll
  for (int ks = 0; ks < 2; ++ks) {
    const float* qp = Qb + n16 * D + ks * 32 + quad * 8;
    float4 x = *(const float4*)qp;
    float4 y = *(const float4*)(qp + 4);
    bf16x8 a;
    a[0] = (short)bf16c(x.x * 0.125f); a[1] = (short)bf16c(x.y * 0.125f);
    a[2] = (short)bf16c(x.z * 0.125f); a[3] = (short)bf16c(x.w * 0.125f);
    a[4] = (short)bf16c(y.x * 0.125f); a[5] = (short)bf16c(y.y * 0.125f);
    a[6] = (short)bf16c(y.z * 0.125f); a[7] = (short)bf16c(y.w * 0.125f);
    aq[ks] = a;
  }

  f32x4 o[4];
#pragma unroll
  for (int nt = 0; nt < 4; ++nt) o[nt] = (f32x4){0.f, 0.f, 0.f, 0.f};
  float rs[4] = {0.f, 0.f, 0.f, 0.f};

  for (int kt = 0; kt < S / BK; ++kt) {
    const int k0 = kt * BK;

    // ---- global loads for this tile (no LDS yet; overlap with barrier) ----
    float4 kld[4], vld[4];
#pragma unroll
    for (int r = 0; r < 4; ++r) {
      int kd4 = t & 15, kkey = (t >> 4) + r * 16;
      kld[r] = *(const float4*)(Kb + (size_t)(k0 + kkey) * D + kd4 * 4);
      int vkey = (t & 15) + r * 16, vd4 = t >> 4;
      vld[r] = *(const float4*)(Vb + (size_t)(k0 + vkey) * D + vd4 * 4);
    }
    float mk[4][4];
#pragma unroll
    for (int nt = 0; nt < 4; ++nt)
#pragma unroll
      for (int r = 0; r < 4; ++r)
        mk[nt][r] = Mb[(size_t)(quad * 4 + r) * S + k0 + nt * 16 + n16];

    __syncthreads();  // prev tile's LDS reads complete before overwrite

    // ---- stage K: [key][d], packed b64 writes ----
#pragma unroll
    for (int r = 0; r < 4; ++r) {
      int kd4 = t & 15, kkey = (t >> 4) + r * 16;
      uint2 w;
      w.x = pk2(kld[r].x, kld[r].y);
      w.y = pk2(kld[r].z, kld[r].w);
      *(uint2*)(sK + kkey * STR + kd4 * 4) = w;
    }
    // ---- stage V transposed: [d][key], lane-pair shuffle pack ----
#pragma unroll
    for (int r = 0; r < 4; ++r) {
      int vkey = (t & 15) + r * 16, vd4 = t >> 4;
      float4 v = vld[r];
      float o0 = __shfl_xor(v.x, 1), o1 = __shfl_xor(v.y, 1);
      float o2 = __shfl_xor(v.z, 1), o3 = __shfl_xor(v.w, 1);
      // even lane handles d = 4*vd4+{0,1}; odd lane d = 4*vd4+{2,3}
      float a0 = odd ? o2 : v.x, b0 = odd ? v.z : o0;
      float a1 = odd ? o3 : v.y, b1 = odd ? v.w : o1;
      int dd = 4 * vd4 + (odd ? 2 : 0);
      int kp = vkey & ~1;
      *(unsigned*)(sVt + dd * STR + kp)       = pk2(a0, b0);
      *(unsigned*)(sVt + (dd + 1) * STR + kp) = pk2(a1, b1);
    }
    __syncthreads();  // staging visible

    // ---- S = Q K^T : B[k=d][n=key] from sK[key][d] ----
    f32x4 sc[4];
#pragma unroll
    for (int nt = 0; nt < 4; ++nt) {
      sc[nt] = (f32x4){0.f, 0.f, 0.f, 0.f};
      bf16x8 bk0 = *(const bf16x8*)(sK + (nt * 16 + n16) * STR + quad * 8);
      bf16x8 bk1 = *(const bf16x8*)(sK + (nt * 16 + n16) * STR + 32 + quad * 8);
      sc[nt] = __builtin_amdgcn_mfma_f32_16x16x32_bf16(aq[0], bk0, sc[nt], 0, 0, 0);
      sc[nt] = __builtin_amdgcn_mfma_f32_16x16x32_bf16(aq[1], bk1, sc[nt], 0, 0, 0);
    }

    // ---- p = exp(s)*mask; row-sum partials; pack P -> LDS [m][k] ----
#pragma unroll
    for (int nt = 0; nt < 4; ++nt) {
      float pr[4];
#pragma unroll
      for (int r = 0; r < 4; ++r) {
        pr[r] = __expf(sc[nt][r]) * mk[nt][r];
        rs[r] += pr[r];
      }
      float po[4];
#pragma unroll
      for (int r = 0; r < 4; ++r) po[r] = __shfl_xor(pr[r], 1);
      // even lane writes rows quad*4+{0,1}; odd writes quad*4+{2,3}; cols (kp,kp+1)
      float a0 = odd ? po[2] : pr[0], b0 = odd ? pr[2] : po[0];
      float a1 = odd ? po[3] : pr[1], b1 = odd ? pr[3] : po[1];
      int m0 = wave * 16 + quad * 4 + (odd ? 2 : 0);
      int kp = nt * 16 + (n16 & ~1);
      *(unsigned*)(sP + m0 * STR + kp)       = pk2(a0, b0);
      *(unsigned*)(sP + (m0 + 1) * STR + kp) = pk2(a1, b1);
    }
    __syncthreads();  // sP visible (wave-private, but barrier keeps it simple+safe)

    // ---- O += P V : A[m][k]=sP, B[k=key][n=d] from sVt[d][key] ----
    bf16x8 ap0 = *(const bf16x8*)(sP + (wave * 16 + n16) * STR + quad * 8);
    bf16x8 ap1 = *(const bf16x8*)(sP + (wave * 16 + n16) * STR + 32 + quad * 8);
#pragma unroll
    for (int nt = 0; nt < 4; ++nt) {
      bf16x8 bv0 = *(const bf16x8*)(sVt + (nt * 16 + n16) * STR + quad * 8);
      bf16x8 bv1 = *(const bf16x8*)(sVt + (nt * 16 + n16) * STR + 32 + quad * 8);
      o[nt] = __builtin_amdgcn_mfma_f32_16x16x32_bf16(ap0, bv0, o[nt], 0, 0, 0);
      o[nt] = __builtin_amdgcn_mfma_f32_16x16x32_bf16(ap1, bv1, o[nt], 0, 0, 0);
    }
  }

  // ---- normalize: reduce row sums over the 16 n-lanes of each quad ----
  float inv[4];
#pragma unroll
  for (int r = 0; r < 4; ++r) {
    float v = rs[r];
    v += __shfl_xor(v, 1);
    v += __shfl_xor(v, 2);
    v += __shfl_xor(v, 4);
    v += __shfl_xor(v, 8);
    inv[r] = 1.0f / (v + 1e-8f);
  }

  float* Ob = Og + ((size_t)bh * S + q0 + wave * 16) * D;
#pragma unroll
  for (int nt = 0; nt < 4; ++nt)
#pragma unroll
    for (int r = 0; r < 4; ++r)
      Ob[(size_t)(quad * 4 + r) * D + nt * 16 + n16] = o[nt][r] * inv[r];
}
} // namespace

extern "C" void kernel_launch(void* const* d_in, const int* in_sizes, int n_in,
                              void* d_out, int out_size, void* d_ws, size_t ws_size,
                              hipStream_t stream) {
  const float* Q = (const float*)d_in[0];
  const float* K = (const float*)d_in[1];
  const float* V = (const float*)d_in[2];
  const float* M = (const float*)d_in[3];
  float* O = (float*)d_out;
  dim3 grid(S / BQ, 4 * 16);
  attn_mfma<<<grid, NT, 0, stream>>>(Q, K, V, M, O);
}

// Round 3
// 320.396 us; speedup vs baseline: 3.3386x; 1.2826x over previous
//
#include <hip/hip_runtime.h>

namespace {
constexpr int S  = 2048;
constexpr int D  = 64;
constexpr int BQ = 64;
constexpr int BK = 64;
constexpr int NT = 256;
constexpr int NKT = S / BK;       // 32 key tiles
constexpr int PSTR = 72;          // sP stride (bf16 elems): 144 B rows, 16B-aligned

typedef short bf16x8 __attribute__((ext_vector_type(8)));
typedef float f32x4  __attribute__((ext_vector_type(4)));

__device__ inline unsigned short bf16c(float x) {
  __bf16 h = (__bf16)x;
  return __builtin_bit_cast(unsigned short, h);
}
__device__ inline unsigned pk2(float a, float b) {
  return (unsigned)bf16c(a) | ((unsigned)bf16c(b) << 16);
}
__device__ inline void gld_lds16(const void* g, void* l) {
  __builtin_amdgcn_global_load_lds(
      (const __attribute__((address_space(1))) unsigned int*)g,
      (__attribute__((address_space(3))) unsigned int*)l, 16, 0, 0);
}

// ---- prep: K fp32 [bh][key][d] -> bf16, granule-swizzled rows ----
__global__ __launch_bounds__(256) void prep_k(const float* __restrict__ K,
                                              unsigned short* __restrict__ Kws) {
  int gid = blockIdx.x * 256 + threadIdx.x;   // 64*2048*8 granules
  int row = gid >> 3;                         // bh*2048 + key
  int g   = gid & 7;
  const float* src = K + (size_t)row * 64 + g * 8;
  float4 a = *(const float4*)src;
  float4 b = *(const float4*)(src + 4);
  uint4 w;
  w.x = pk2(a.x, a.y); w.y = pk2(a.z, a.w);
  w.z = pk2(b.x, b.y); w.w = pk2(b.z, b.w);
  *(uint4*)(Kws + (size_t)row * 64 + ((g ^ (row & 7)) * 8)) = w;
}

// ---- prep: V fp32 [bh][key][d] -> bf16 transposed tile-blocked [bh][kt][d][key], swizzled ----
__global__ __launch_bounds__(256) void prep_v(const float* __restrict__ V,
                                              unsigned short* __restrict__ Vws) {
  __shared__ float tl[64 * 68];
  const int t = threadIdx.x;
  const size_t tile = blockIdx.x;             // bh*32 + kt
  const float* src = V + tile * (64 * 64);    // contiguous 64keys x 64d
#pragma unroll
  for (int rep = 0; rep < 4; ++rep) {
    int idx = t + rep * 256;                  // 0..1023 float4s
    int row = idx >> 4, d4 = idx & 15;
    float4 v = *(const float4*)(src + row * 64 + d4 * 4);
    *(float4*)(tl + row * 68 + d4 * 4) = v;   // 68*4=272 B stride, 16B-aligned
  }
  __syncthreads();
  unsigned short* dstT = Vws + tile * (64 * 64);
#pragma unroll
  for (int rep = 0; rep < 2; ++rep) {
    int gid = t + rep * 256;                  // 0..511 granules
    int d  = gid >> 3;
    int kg = gid & 7;                         // logical key-granule
    float x[8];
#pragma unroll
    for (int j = 0; j < 8; ++j) x[j] = tl[(kg * 8 + j) * 68 + d];
    uint4 w;
    w.x = pk2(x[0], x[1]); w.y = pk2(x[2], x[3]);
    w.z = pk2(x[4], x[5]); w.w = pk2(x[6], x[7]);
    *(uint4*)(dstT + d * 64 + ((kg ^ (d & 7)) * 8)) = w;
  }
}

// ---- main attention ----
__global__ __launch_bounds__(NT, 3)
void attn2(const float* __restrict__ Qg, const float* __restrict__ Mg,
           const unsigned short* __restrict__ Kws,
           const unsigned short* __restrict__ Vws,
           float* __restrict__ Og) {
  __shared__ __align__(16) unsigned short sK[2][BK * D];   // 8 KB each, swizzled rows
  __shared__ __align__(16) unsigned short sV[2][BK * D];
  __shared__ __align__(16) unsigned short sP[BQ * PSTR];   // wave-private 16-row bands

  const int t    = threadIdx.x;
  const int wave = t >> 6;
  const int lane = t & 63;
  const int quad = lane >> 4;
  const int n16  = lane & 15;

  const int bh = blockIdx.y;
  const int b  = bh >> 4;
  const int q0 = blockIdx.x * BQ;

  const unsigned short* Kb = Kws + (size_t)bh * S * D;
  const unsigned short* Vb = Vws + (size_t)bh * S * D;     // tile-blocked
  const float* Mlane = Mg + (size_t)b * S * S
                     + (size_t)(q0 + wave * 16 + quad * 4) * S + n16;

  // Q A-frags from fp32 global, pre-scaled by 1/8
  const float* Qb = Qg + ((size_t)bh * S + q0 + wave * 16) * D;
  bf16x8 aq[2];
#pragma unroll
  for (int ks = 0; ks < 2; ++ks) {
    const float* qp = Qb + n16 * D + ks * 32 + quad * 8;
    float4 x = *(const float4*)qp;
    float4 y = *(const float4*)(qp + 4);
    bf16x8 a;
    a[0] = (short)bf16c(x.x * 0.125f); a[1] = (short)bf16c(x.y * 0.125f);
    a[2] = (short)bf16c(x.z * 0.125f); a[3] = (short)bf16c(x.w * 0.125f);
    a[4] = (short)bf16c(y.x * 0.125f); a[5] = (short)bf16c(y.y * 0.125f);
    a[6] = (short)bf16c(y.z * 0.125f); a[7] = (short)bf16c(y.w * 0.125f);
    aq[ks] = a;
  }

  f32x4 o[4];
#pragma unroll
  for (int nt = 0; nt < 4; ++nt) o[nt] = (f32x4){0.f, 0.f, 0.f, 0.f};
  float rs[4] = {0.f, 0.f, 0.f, 0.f};
  float mk[2][16];

  // ---- prologue: stage tile 0, prefetch mask 0 ----
  {
    const unsigned short* kg = Kb + wave * 1024 + lane * 8;
    gld_lds16(kg,       &sK[0][wave * 1024]);
    gld_lds16(kg + 512, &sK[0][wave * 1024 + 512]);
    const unsigned short* vg = Vb + wave * 1024 + lane * 8;
    gld_lds16(vg,       &sV[0][wave * 1024]);
    gld_lds16(vg + 512, &sV[0][wave * 1024 + 512]);
  }
#pragma unroll
  for (int nt = 0; nt < 4; ++nt)
#pragma unroll
    for (int r = 0; r < 4; ++r)
      mk[0][nt * 4 + r] = Mlane[(size_t)r * S + nt * 16];

#pragma unroll 2
  for (int kt = 0; kt < NKT; ++kt) {
    const int cur = kt & 1, nxt = cur ^ 1;
    __syncthreads();   // drains tile-kt loads; prior reads of buf[nxt] done

    if (kt + 1 < NKT) {   // stage kt+1 into the other buffer
      const unsigned short* kg = Kb + (size_t)(kt + 1) * (BK * D) + wave * 1024 + lane * 8;
      gld_lds16(kg,       &sK[nxt][wave * 1024]);
      gld_lds16(kg + 512, &sK[nxt][wave * 1024 + 512]);
      const unsigned short* vg = Vb + (size_t)(kt + 1) * (BK * D) + wave * 1024 + lane * 8;
      gld_lds16(vg,       &sV[nxt][wave * 1024]);
      gld_lds16(vg + 512, &sV[nxt][wave * 1024 + 512]);
    }

    // ---- S = Q K^T ----
    f32x4 sc[4];
#pragma unroll
    for (int nt = 0; nt < 4; ++nt) {
      const int row = nt * 16 + n16, sw = row & 7;
      bf16x8 bk0 = *(const bf16x8*)(sK[cur] + row * 64 + ((quad) ^ sw) * 8);
      bf16x8 bk1 = *(const bf16x8*)(sK[cur] + row * 64 + ((quad + 4) ^ sw) * 8);
      sc[nt] = (f32x4){0.f, 0.f, 0.f, 0.f};
      sc[nt] = __builtin_amdgcn_mfma_f32_16x16x32_bf16(aq[0], bk0, sc[nt], 0, 0, 0);
      sc[nt] = __builtin_amdgcn_mfma_f32_16x16x32_bf16(aq[1], bk1, sc[nt], 0, 0, 0);
    }

    // prefetch next tile's mask into registers
    if (kt + 1 < NKT) {
#pragma unroll
      for (int nt = 0; nt < 4; ++nt)
#pragma unroll
        for (int r = 0; r < 4; ++r)
          mk[nxt][nt * 4 + r] = Mlane[(size_t)r * S + (kt + 1) * 64 + nt * 16];
    }

    // ---- p = exp(s)*mask; rowsum of rounded p; write P (bf16) to wave-private sP ----
#pragma unroll
    for (int nt = 0; nt < 4; ++nt)
#pragma unroll
      for (int r = 0; r < 4; ++r) {
        float p = __expf(sc[nt][r]) * mk[cur][nt * 4 + r];
        unsigned short u = bf16c(p);
        rs[r] += __builtin_bit_cast(float, (unsigned)u << 16);
        sP[(wave * 16 + quad * 4 + r) * PSTR + nt * 16 + n16] = u;
      }

    // ---- O += P V (in-wave LDS ordering; no barrier needed) ----
    const int prow = wave * 16 + n16;
    bf16x8 ap0 = *(const bf16x8*)(sP + prow * PSTR + quad * 8);
    bf16x8 ap1 = *(const bf16x8*)(sP + prow * PSTR + 32 + quad * 8);
#pragma unroll
    for (int nt = 0; nt < 4; ++nt) {
      const int row = nt * 16 + n16, sw = row & 7;
      bf16x8 bv0 = *(const bf16x8*)(sV[cur] + row * 64 + ((quad) ^ sw) * 8);
      bf16x8 bv1 = *(const bf16x8*)(sV[cur] + row * 64 + ((quad + 4) ^ sw) * 8);
      o[nt] = __builtin_amdgcn_mfma_f32_16x16x32_bf16(ap0, bv0, o[nt], 0, 0, 0);
      o[nt] = __builtin_amdgcn_mfma_f32_16x16x32_bf16(ap1, bv1, o[nt], 0, 0, 0);
    }
  }

  // ---- normalize + store ----
  float inv[4];
#pragma unroll
  for (int r = 0; r < 4; ++r) {
    float v = rs[r];
    v += __shfl_xor(v, 1);
    v += __shfl_xor(v, 2);
    v += __shfl_xor(v, 4);
    v += __shfl_xor(v, 8);
    inv[r] = 1.0f / (v + 1e-8f);
  }
  float* Ob = Og + ((size_t)bh * S + q0 + wave * 16) * D;
#pragma unroll
  for (int nt = 0; nt < 4; ++nt)
#pragma unroll
    for (int r = 0; r < 4; ++r)
      Ob[(size_t)(quad * 4 + r) * D + nt * 16 + n16] = o[nt][r] * inv[r];
}
} // namespace

extern "C" void kernel_launch(void* const* d_in, const int* in_sizes, int n_in,
                              void* d_out, int out_size, void* d_ws, size_t ws_size,
                              hipStream_t stream) {
  const float* Q = (const float*)d_in[0];
  const float* K = (const float*)d_in[1];
  const float* V = (const float*)d_in[2];
  const float* M = (const float*)d_in[3];
  float* O = (float*)d_out;

  unsigned short* Kws = (unsigned short*)d_ws;
  unsigned short* Vws = Kws + (size_t)64 * S * D;   // 16.78 MB each

  prep_k<<<dim3(64 * S * D / 8 / 256), 256, 0, stream>>>(K, Kws);
  prep_v<<<dim3(64 * NKT), 256, 0, stream>>>(V, Vws);
  attn2<<<dim3(S / BQ, 64), NT, 0, stream>>>(Q, M, Kws, Vws, O);
}

// Round 4
// 295.680 us; speedup vs baseline: 3.6177x; 1.0836x over previous
//
#include <hip/hip_runtime.h>

namespace {
constexpr int S  = 2048;
constexpr int D  = 64;
constexpr int BQ = 128;   // q-rows per block (16 per wave, 8 waves)
constexpr int BK = 64;
constexpr int NT = 512;
constexpr int NKT = S / BK;     // 32 key tiles
constexpr int PSTR = 72;        // sP stride (bf16): 144 B rows

typedef short bf16x8 __attribute__((ext_vector_type(8)));
typedef float f32x4  __attribute__((ext_vector_type(4)));

__device__ inline unsigned short bf16c(float x) {
  __bf16 h = (__bf16)x;
  return __builtin_bit_cast(unsigned short, h);
}
__device__ inline unsigned pk2(float a, float b) {
  return (unsigned)bf16c(a) | ((unsigned)bf16c(b) << 16);
}
__device__ inline void gld_lds16(const void* g, void* l) {
  __builtin_amdgcn_global_load_lds(
      (const __attribute__((address_space(1))) unsigned int*)g,
      (__attribute__((address_space(3))) unsigned int*)l, 16, 0, 0);
}

// ---- prep: K fp32 [bh][key][d] -> bf16, granule-swizzled rows ----
__global__ __launch_bounds__(256) void prep_k(const float* __restrict__ K,
                                              unsigned short* __restrict__ Kws) {
  int gid = blockIdx.x * 256 + threadIdx.x;
  int row = gid >> 3;
  int g   = gid & 7;
  const float* src = K + (size_t)row * 64 + g * 8;
  float4 a = *(const float4*)src;
  float4 b = *(const float4*)(src + 4);
  uint4 w;
  w.x = pk2(a.x, a.y); w.y = pk2(a.z, a.w);
  w.z = pk2(b.x, b.y); w.w = pk2(b.z, b.w);
  *(uint4*)(Kws + (size_t)row * 64 + ((g ^ (row & 7)) * 8)) = w;
}

// ---- prep: V -> bf16 transposed tile-blocked [bh][kt][d][key], swizzled ----
__global__ __launch_bounds__(256) void prep_v(const float* __restrict__ V,
                                              unsigned short* __restrict__ Vws) {
  __shared__ float tl[64 * 68];
  const int t = threadIdx.x;
  const size_t tile = blockIdx.x;             // bh*32 + kt
  const float* src = V + tile * (64 * 64);
#pragma unroll
  for (int rep = 0; rep < 4; ++rep) {
    int idx = t + rep * 256;
    int row = idx >> 4, d4 = idx & 15;
    float4 v = *(const float4*)(src + row * 64 + d4 * 4);
    *(float4*)(tl + row * 68 + d4 * 4) = v;
  }
  __syncthreads();
  unsigned short* dstT = Vws + tile * (64 * 64);
#pragma unroll
  for (int rep = 0; rep < 2; ++rep) {
    int d  = (t & 31) + rep * 32;   // lanes spread over d -> conflict-free reads
    int kg = t >> 5;                // 0..7
    float x[8];
#pragma unroll
    for (int j = 0; j < 8; ++j) x[j] = tl[(kg * 8 + j) * 68 + d];
    uint4 w;
    w.x = pk2(x[0], x[1]); w.y = pk2(x[2], x[3]);
    w.z = pk2(x[4], x[5]); w.w = pk2(x[6], x[7]);
    *(uint4*)(dstT + d * 64 + ((kg ^ (d & 7)) * 8)) = w;
  }
}

// ---- prep: mask fp32 [b][q][k] -> u8 lane-blocked [b][kt][qband][quad][n16][r*4+nt] ----
__global__ __launch_bounds__(256) void prep_m(const float* __restrict__ M,
                                              unsigned char* __restrict__ M2) {
  size_t gid = (size_t)blockIdx.x * 256 + threadIdx.x;
  int n16  = gid & 15;
  int quad = (gid >> 4) & 3;
  size_t rest = gid >> 6;
  int qband = rest & 127;
  int kt    = (rest >> 7) & 31;
  int b     = rest >> 12;
  unsigned wds[4];
#pragma unroll
  for (int r = 0; r < 4; ++r) {
    int q = qband * 16 + quad * 4 + r;
    const float* src = M + ((size_t)b * S + q) * S + kt * 64 + n16;
    unsigned w = 0;
#pragma unroll
    for (int nt = 0; nt < 4; ++nt)
      w |= (src[nt * 16] != 0.0f ? 1u : 0u) << (8 * nt);
    wds[r] = w;
  }
  uint4 out = make_uint4(wds[0], wds[1], wds[2], wds[3]);
  *(uint4*)(M2 + gid * 16) = out;
}

// ---- main attention ----
__global__ __launch_bounds__(NT, 6)
void attn3(const float* __restrict__ Qg, const unsigned char* __restrict__ M2,
           const unsigned short* __restrict__ Kws,
           const unsigned short* __restrict__ Vws,
           float* __restrict__ Og) {
  __shared__ __align__(16) unsigned short sK[2][BK * D];   // 8 KB each
  __shared__ __align__(16) unsigned short sV[2][BK * D];
  __shared__ __align__(16) unsigned short sP[BQ * PSTR];   // wave-private 16-row bands

  const int t    = threadIdx.x;
  const int wave = t >> 6;
  const int lane = t & 63;
  const int quad = lane >> 4;
  const int n16  = lane & 15;

  const int bh = blockIdx.y;
  const int b  = bh >> 4;
  const int q0 = blockIdx.x * BQ;
  const int qband = blockIdx.x * 8 + wave;

  const unsigned short* Kb = Kws + (size_t)bh * S * D;
  const unsigned short* Vb = Vws + (size_t)bh * S * D;
  // mask: one dwordx4 per tile per lane
  const unsigned char* Mp = M2
      + ((((size_t)b * NKT) * 128 + qband) * 4 + quad) * 256 + n16 * 16;
  constexpr size_t MKT = (size_t)128 * 4 * 16 * 16;   // per-kt stride (bytes)

  // Q A-frags, pre-scaled by 1/8
  const float* Qb = Qg + ((size_t)bh * S + q0 + wave * 16) * D;
  bf16x8 aq[2];
#pragma unroll
  for (int ks = 0; ks < 2; ++ks) {
    const float* qp = Qb + n16 * D + ks * 32 + quad * 8;
    float4 x = *(const float4*)qp;
    float4 y = *(const float4*)(qp + 4);
    bf16x8 a;
    a[0] = (short)bf16c(x.x * 0.125f); a[1] = (short)bf16c(x.y * 0.125f);
    a[2] = (short)bf16c(x.z * 0.125f); a[3] = (short)bf16c(x.w * 0.125f);
    a[4] = (short)bf16c(y.x * 0.125f); a[5] = (short)bf16c(y.y * 0.125f);
    a[6] = (short)bf16c(y.z * 0.125f); a[7] = (short)bf16c(y.w * 0.125f);
    aq[ks] = a;
  }

  f32x4 o[4];
#pragma unroll
  for (int nt = 0; nt < 4; ++nt) o[nt] = (f32x4){0.f, 0.f, 0.f, 0.f};
  float rs[4] = {0.f, 0.f, 0.f, 0.f};
  uint4 mk[2];

  // ---- prologue: stage tile 0 (1 KB per wave per tensor), mask 0 ----
  gld_lds16(Kb + wave * 512 + lane * 8, &sK[0][wave * 512]);
  gld_lds16(Vb + wave * 512 + lane * 8, &sV[0][wave * 512]);
  mk[0] = *(const uint4*)Mp;

#pragma unroll 2
  for (int kt = 0; kt < NKT; ++kt) {
    const int cur = kt & 1, nxt = cur ^ 1;
    __syncthreads();   // drains tile-kt loads; prior reads of buf[nxt] done

    if (kt + 1 < NKT) {
      gld_lds16(Kb + (size_t)(kt + 1) * (BK * D) + wave * 512 + lane * 8,
                &sK[nxt][wave * 512]);
      gld_lds16(Vb + (size_t)(kt + 1) * (BK * D) + wave * 512 + lane * 8,
                &sV[nxt][wave * 512]);
      mk[nxt] = *(const uint4*)(Mp + (size_t)(kt + 1) * MKT);
    }

    // ---- S = Q K^T ----
    f32x4 sc[4];
#pragma unroll
    for (int nt = 0; nt < 4; ++nt) {
      const int row = nt * 16 + n16, sw = row & 7;
      bf16x8 bk0 = *(const bf16x8*)(sK[cur] + row * 64 + ((quad) ^ sw) * 8);
      bf16x8 bk1 = *(const bf16x8*)(sK[cur] + row * 64 + ((quad + 4) ^ sw) * 8);
      sc[nt] = (f32x4){0.f, 0.f, 0.f, 0.f};
      sc[nt] = __builtin_amdgcn_mfma_f32_16x16x32_bf16(aq[0], bk0, sc[nt], 0, 0, 0);
      sc[nt] = __builtin_amdgcn_mfma_f32_16x16x32_bf16(aq[1], bk1, sc[nt], 0, 0, 0);
    }

    // ---- p = exp(s)*mask; rowsum of rounded p; P -> wave-private sP ----
    const unsigned mw[4] = {mk[cur].x, mk[cur].y, mk[cur].z, mk[cur].w};
#pragma unroll
    for (int nt = 0; nt < 4; ++nt)
#pragma unroll
      for (int r = 0; r < 4; ++r) {
        float m = (float)((mw[r] >> (8 * nt)) & 0xffu);
        float p = __expf(sc[nt][r]) * m;
        unsigned short u = bf16c(p);
        rs[r] += __builtin_bit_cast(float, (unsigned)u << 16);
        sP[(wave * 16 + quad * 4 + r) * PSTR + nt * 16 + n16] = u;
      }

    // ---- O += P V (in-wave LDS ordering; no barrier) ----
    const int prow = wave * 16 + n16;
    bf16x8 ap0 = *(const bf16x8*)(sP + prow * PSTR + quad * 8);
    bf16x8 ap1 = *(const bf16x8*)(sP + prow * PSTR + 32 + quad * 8);
#pragma unroll
    for (int nt = 0; nt < 4; ++nt) {
      const int row = nt * 16 + n16, sw = row & 7;
      bf16x8 bv0 = *(const bf16x8*)(sV[cur] + row * 64 + ((quad) ^ sw) * 8);
      bf16x8 bv1 = *(const bf16x8*)(sV[cur] + row * 64 + ((quad + 4) ^ sw) * 8);
      o[nt] = __builtin_amdgcn_mfma_f32_16x16x32_bf16(ap0, bv0, o[nt], 0, 0, 0);
      o[nt] = __builtin_amdgcn_mfma_f32_16x16x32_bf16(ap1, bv1, o[nt], 0, 0, 0);
    }
  }

  // ---- normalize + store ----
  float inv[4];
#pragma unroll
  for (int r = 0; r < 4; ++r) {
    float v = rs[r];
    v += __shfl_xor(v, 1);
    v += __shfl_xor(v, 2);
    v += __shfl_xor(v, 4);
    v += __shfl_xor(v, 8);
    inv[r] = 1.0f / (v + 1e-8f);
  }
  float* Ob = Og + ((size_t)bh * S + q0 + wave * 16) * D;
#pragma unroll
  for (int nt = 0; nt < 4; ++nt)
#pragma unroll
    for (int r = 0; r < 4; ++r)
      Ob[(size_t)(quad * 4 + r) * D + nt * 16 + n16] = o[nt][r] * inv[r];
}
} // namespace

extern "C" void kernel_launch(void* const* d_in, const int* in_sizes, int n_in,
                              void* d_out, int out_size, void* d_ws, size_t ws_size,
                              hipStream_t stream) {
  const float* Q = (const float*)d_in[0];
  const float* K = (const float*)d_in[1];
  const float* V = (const float*)d_in[2];
  const float* M = (const float*)d_in[3];
  float* O = (float*)d_out;

  unsigned short* Kws = (unsigned short*)d_ws;
  unsigned short* Vws = Kws + (size_t)64 * S * D;                 // +16.78 MB
  unsigned char*  M2  = (unsigned char*)(Vws + (size_t)64 * S * D); // +16.78 MB

  prep_k<<<dim3(64 * S * D / 8 / 256), 256, 0, stream>>>(K, Kws);
  prep_v<<<dim3(64 * NKT), 256, 0, stream>>>(V, Vws);
  prep_m<<<dim3(4 * NKT * 128 * 4 * 16 / 256), 256, 0, stream>>>(M, M2);
  attn3<<<dim3(S / BQ, 64), NT, 0, stream>>>(Q, M2, Kws, Vws, O);
}